// Round 1
// baseline (33711.334 us; speedup 1.0000x reference)
//
#include <hip/hip_runtime.h>
#include <cmath>

#define AGENT __HIP_MEMORY_SCOPE_AGENT

// Problem constants
// B=4, S=512, I=H=768, 3H=2304, E=8, K=2, L=2, tokens=2048, assignments=4096

// ---------------- reset ----------------
__global__ void reset_kernel(int* __restrict__ flags, int* __restrict__ counts,
                             float* __restrict__ hbuf0) {
  int i = blockIdx.x * 256 + threadIdx.x;
  if (i < 6208) flags[i] = 0;          // 192*32 flags + release + slack
  if (i < 16) counts[i] = 0;           // counts[2][8]
  if (i < 3072) hbuf0[i] = 0.f;        // h0 = zeros (layer 0)
}

// ---------------- GEMM: C = op(A @ B^T + bias) ----------------
// A [M x Kd] row-major (lda), B [N x Kd] row-major, C rows scattered if GATHER.
// Tile 128x128x16, 256 threads, 8x8 acc/thread (2x2 blocks of 4x4).
template<bool GATHER, bool SHIFT, bool RELU, bool GATE>
__global__ __launch_bounds__(256)
void gemm_nt(const float* __restrict__ A, const float* __restrict__ Bw,
             const float* __restrict__ bias, float* __restrict__ C,
             int M, int N, int Kd, int lda, int ldc,
             const int* __restrict__ list, const int* __restrict__ count,
             const float* __restrict__ gates, long wstride, int bstride)
{
  __shared__ float As[16][132];
  __shared__ float Bs[16][132];
  __shared__ int rowlist[128];

  int e = 0, cnt = M;
  if constexpr (GATHER) { e = blockIdx.z; cnt = count[e]; }
  int mbase = blockIdx.y * 128;
  if (mbase >= cnt) return;
  int nbase = blockIdx.x * 128;
  const float* Bp = Bw + (size_t)e * (size_t)wstride;
  const float* biasp = bias + (size_t)e * (size_t)bstride;

  int tid = threadIdx.x;
  if constexpr (GATHER) {
    if (tid < 128) {
      int r = mbase + tid;
      rowlist[tid] = list[e * 4096 + (r < cnt ? r : cnt - 1)];
    }
    __syncthreads();
  }

  int tx = tid & 15, ty = tid >> 4;

  const float* ap[2];
  const float* bp[2];
  int ldst[2];
#pragma unroll
  for (int i = 0; i < 2; ++i) {
    int v = tid + 256 * i;
    int row = v >> 2, kq = v & 3;
    const float* a0;
    if constexpr (GATHER) {
      int aidx = rowlist[row];
      int sr = SHIFT ? (aidx >> 1) : aidx;
      a0 = A + (size_t)sr * lda;
    } else {
      a0 = A + (size_t)(mbase + row) * lda;
    }
    ap[i] = a0 + kq * 4;
    bp[i] = Bp + (size_t)(nbase + row) * Kd + kq * 4;
    ldst[i] = kq * 4 * 132 + row;
  }

  float acc[8][8];
#pragma unroll
  for (int i = 0; i < 8; ++i)
#pragma unroll
    for (int j = 0; j < 8; ++j) acc[i][j] = 0.f;

  for (int kb = 0; kb < Kd; kb += 16) {
    float4 av[2], bv[2];
#pragma unroll
    for (int i = 0; i < 2; ++i) {
      av[i] = *(const float4*)(ap[i] + kb);
      bv[i] = *(const float4*)(bp[i] + kb);
    }
    if (kb) __syncthreads();
#pragma unroll
    for (int i = 0; i < 2; ++i) {
      float* ad = &As[0][0] + ldst[i];
      ad[0] = av[i].x; ad[132] = av[i].y; ad[264] = av[i].z; ad[396] = av[i].w;
      float* bd = &Bs[0][0] + ldst[i];
      bd[0] = bv[i].x; bd[132] = bv[i].y; bd[264] = bv[i].z; bd[396] = bv[i].w;
    }
    __syncthreads();
#pragma unroll
    for (int kk = 0; kk < 16; ++kk) {
      float a[8], b[8];
      *(float4*)&a[0] = *(const float4*)&As[kk][ty * 4];
      *(float4*)&a[4] = *(const float4*)&As[kk][ty * 4 + 64];
      *(float4*)&b[0] = *(const float4*)&Bs[kk][tx * 4];
      *(float4*)&b[4] = *(const float4*)&Bs[kk][tx * 4 + 64];
#pragma unroll
      for (int i = 0; i < 8; ++i)
#pragma unroll
        for (int j = 0; j < 8; ++j)
          acc[i][j] = fmaf(a[i], b[j], acc[i][j]);
    }
  }

#pragma unroll
  for (int i = 0; i < 8; ++i) {
    int lrow = ty * 4 + (i & 3) + ((i >> 2) << 6);
    int grow = mbase + lrow;
    bool ok = true;
    int orow = grow;
    float gs = 1.f;
    if constexpr (GATHER) {
      ok = (grow < cnt);
      int aidx = rowlist[lrow];
      orow = aidx;
      if constexpr (GATE) gs = gates[aidx];
    }
    if (ok) {
#pragma unroll
      for (int q = 0; q < 2; ++q) {
        int col = nbase + tx * 4 + (q << 6);
        float4 bb = *(const float4*)&biasp[col];
        float r0 = acc[i][q * 4 + 0] + bb.x;
        float r1 = acc[i][q * 4 + 1] + bb.y;
        float r2 = acc[i][q * 4 + 2] + bb.z;
        float r3 = acc[i][q * 4 + 3] + bb.w;
        if constexpr (RELU) {
          r0 = fmaxf(r0, 0.f); r1 = fmaxf(r1, 0.f);
          r2 = fmaxf(r2, 0.f); r3 = fmaxf(r3, 0.f);
        }
        if constexpr (GATE) { r0 *= gs; r1 *= gs; r2 *= gs; r3 *= gs; }
        float4 st = make_float4(r0, r1, r2, r3);
        *(float4*)&C[(size_t)orow * ldc + col] = st;
      }
    }
  }
}

// ---------------- GRU persistent kernel ----------------
// 192 WGs x 256 threads = 768 waves; wave w owns output column j = w.
// Whh rows {j, H+j, 2H+j} live in registers (lane holds k-slice of 12).
// Per step: read full h (global, double-buffered), 144 FMA, butterfly reduce,
// lanes 0..3 apply gate math and store, then flag-array grid barrier.
__global__ __launch_bounds__(256)
void gru_kernel(const float* __restrict__ gi, float* __restrict__ h_seq,
                float* __restrict__ hbuf, const float* __restrict__ Whh,
                const float* __restrict__ bhh,
                int* __restrict__ flags, int* __restrict__ release,
                int stepBase)
{
  const int H = 768, S = 512;
  int wg = blockIdx.x;
  int tid = threadIdx.x;
  int wave = tid >> 6;
  int lane = tid & 63;
  int j = wg * 4 + wave;

  float W[3][12];
#pragma unroll
  for (int g = 0; g < 3; ++g) {
    const float* wp = Whh + (size_t)(g * H + j) * H + lane * 12;
    *(float4*)&W[g][0] = *(const float4*)(wp);
    *(float4*)&W[g][4] = *(const float4*)(wp + 4);
    *(float4*)&W[g][8] = *(const float4*)(wp + 8);
  }
  float bh_r = bhh[j], bh_z = bhh[H + j], bh_n = bhh[2 * H + j];

  float h_own = 0.f;
  if (lane < 4) h_own = hbuf[(stepBase & 1) * 3072 + lane * H + j];

  for (int t = 0; t < S; ++t) {
    int gstep = stepBase + t;
    const float* hb = hbuf + (gstep & 1) * 3072;
    float* hw = hbuf + ((gstep + 1) & 1) * 3072;

    float gi_r = 0.f, gi_z = 0.f, gi_n = 0.f;
    if (lane < 4) {
      const float* gp = gi + ((size_t)lane * S + t) * 2304;
      gi_r = gp[j]; gi_z = gp[H + j]; gi_n = gp[2 * H + j];
    }

    float hseg[4][12];
#pragma unroll
    for (int b = 0; b < 4; ++b) {
      const float* hp = hb + b * H + lane * 12;
      *(float4*)&hseg[b][0] = *(const float4*)(hp);
      *(float4*)&hseg[b][4] = *(const float4*)(hp + 4);
      *(float4*)&hseg[b][8] = *(const float4*)(hp + 8);
    }

    float acc[3][4];
#pragma unroll
    for (int g = 0; g < 3; ++g)
#pragma unroll
      for (int b = 0; b < 4; ++b) {
        float s = 0.f;
#pragma unroll
        for (int i = 0; i < 12; ++i) s = fmaf(W[g][i], hseg[b][i], s);
        acc[g][b] = s;
      }
#pragma unroll
    for (int g = 0; g < 3; ++g)
#pragma unroll
      for (int b = 0; b < 4; ++b) {
        float v = acc[g][b];
#pragma unroll
        for (int m = 32; m >= 1; m >>= 1) v += __shfl_xor(v, m);
        acc[g][b] = v;
      }

    if (lane < 4) {
      int b = lane;
      float r = 1.f / (1.f + expf(-(gi_r + acc[0][b] + bh_r)));
      float z = 1.f / (1.f + expf(-(gi_z + acc[1][b] + bh_z)));
      float n = tanhf(gi_n + r * (acc[2][b] + bh_n));
      float hn = (1.f - z) * n + z * h_own;
      h_own = hn;
      hw[b * H + j] = hn;
      h_seq[((size_t)b * S + t) * H + j] = hn;
    }

    // ---- grid barrier (flag array, no atomic contention) ----
    __threadfence();
    __syncthreads();
    int target = gstep + 1;
    if (tid == 0)
      __hip_atomic_store(&flags[wg * 32], target, __ATOMIC_RELEASE, AGENT);
    if (wg == 0 && wave == 0) {
      for (;;) {
        int a = __hip_atomic_load(&flags[lane * 32], __ATOMIC_ACQUIRE, AGENT);
        int b = __hip_atomic_load(&flags[(lane + 64) * 32], __ATOMIC_ACQUIRE, AGENT);
        int c = __hip_atomic_load(&flags[(lane + 128) * 32], __ATOMIC_ACQUIRE, AGENT);
        if (__all(min(a, min(b, c)) >= target)) break;
        __builtin_amdgcn_s_sleep(1);
      }
      if (lane == 0)
        __hip_atomic_store(release, target, __ATOMIC_RELEASE, AGENT);
    }
    if (tid == 0) {
      while (__hip_atomic_load(release, __ATOMIC_ACQUIRE, AGENT) < target)
        __builtin_amdgcn_s_sleep(1);
    }
    __syncthreads();
  }
}

// ---------------- router + top-2 + gates + expert lists ----------------
__global__ __launch_bounds__(64)
void router_kernel(const float* __restrict__ h_seq, const float* __restrict__ rW,
                   const float* __restrict__ rb, int* __restrict__ counts,
                   int* __restrict__ lists, float* __restrict__ gates)
{
  int t = blockIdx.x;       // token 0..2047
  int lane = threadIdx.x;   // 0..63
  const float* hp = h_seq + (size_t)t * 768 + lane * 12;
  float h[12];
  *(float4*)&h[0] = *(const float4*)(hp);
  *(float4*)&h[4] = *(const float4*)(hp + 4);
  *(float4*)&h[8] = *(const float4*)(hp + 8);

  float lg[8];
#pragma unroll
  for (int e = 0; e < 8; ++e) {
    const float* wp = rW + e * 768 + lane * 12;
    float s = 0.f;
#pragma unroll
    for (int i = 0; i < 12; ++i) s = fmaf(h[i], wp[i], s);
#pragma unroll
    for (int m = 32; m >= 1; m >>= 1) s += __shfl_xor(s, m);
    lg[e] = s + rb[e];
  }
  if (lane == 0) {
    float v1 = lg[0]; int e1 = 0;
#pragma unroll
    for (int e = 1; e < 8; ++e) {
      if (lg[e] > v1) { v1 = lg[e]; e1 = e; }
    }
    float v2 = -INFINITY; int es = 0;
#pragma unroll
    for (int e = 0; e < 8; ++e) {
      if (e != e1 && lg[e] > v2) { v2 = lg[e]; es = e; }
    }
    float ed = expf(v2 - v1);
    float g1 = 1.f / (1.f + ed);
    float g2 = ed / (1.f + ed);
    int a0 = t * 2, a1 = t * 2 + 1;
    gates[a0] = g1;
    gates[a1] = g2;
    int p = atomicAdd(&counts[e1], 1);
    lists[e1 * 4096 + p] = a0;
    p = atomicAdd(&counts[es], 1);
    lists[es * 4096 + p] = a1;
  }
}

// ---------------- combine: x_next[t] = ybuf[2t] + ybuf[2t+1] ----------------
__global__ __launch_bounds__(256)
void combine_kernel(const float* __restrict__ ybuf, float* __restrict__ out)
{
  int i = blockIdx.x * 256 + threadIdx.x;     // one float4 each
  int fi = i * 4;                              // < 2048*768
  int t = fi / 768;
  int d = fi % 768;
  float4 y0 = *(const float4*)&ybuf[(size_t)(2 * t) * 768 + d];
  float4 y1 = *(const float4*)&ybuf[(size_t)(2 * t + 1) * 768 + d];
  float4 r = make_float4(y0.x + y1.x, y0.y + y1.y, y0.z + y1.z, y0.w + y1.w);
  *(float4*)&out[fi] = r;
}

// ---------------- host ----------------
extern "C" void kernel_launch(void* const* d_in, const int* in_sizes, int n_in,
                              void* d_out, int out_size, void* d_ws, size_t ws_size,
                              hipStream_t stream) {
  (void)in_sizes; (void)n_in; (void)out_size; (void)ws_size;
  const float* x      = (const float*)d_in[0];
  const float* proj_W = (const float*)d_in[1];
  const float* proj_b = (const float*)d_in[2];
  const float* Wih    = (const float*)d_in[3];
  const float* Whh    = (const float*)d_in[4];
  const float* bih    = (const float*)d_in[5];
  const float* bhh    = (const float*)d_in[6];
  const float* rW     = (const float*)d_in[7];
  const float* rb     = (const float*)d_in[8];
  const float* eW1    = (const float*)d_in[9];
  const float* eb1    = (const float*)d_in[10];
  const float* eW2    = (const float*)d_in[11];
  const float* eb2    = (const float*)d_in[12];
  float* out = (float*)d_out;

  // workspace layout (floats)
  float* f = (float*)d_ws;
  float* h_in  = f;                    // 2048*768
  float* gi    = h_in + 1572864;       // 2048*2304
  float* h_seq = gi + 4718592;         // 2048*768
  float* x_buf = h_seq + 1572864;      // 2048*768
  float* H1    = x_buf + 1572864;      // 4096*3072
  float* ybuf  = H1 + 12582912;        // 4096*768
  float* hbuf  = ybuf + 3145728;       // 2*3072
  float* gates = hbuf + 6144;          // 4096
  int* ints    = (int*)(gates + 4096);
  int* counts  = ints;                 // 16
  int* lists   = ints + 16;            // 8*4096
  int* flags   = ints + 16 + 32768;    // 192*32 + release

  reset_kernel<<<25, 256, 0, stream>>>(flags, counts, hbuf);

  for (int l = 0; l < 2; ++l) {
    const float* xin = l ? x_buf : x;

    dim3 g1(6, 16);
    gemm_nt<false, false, false, false><<<g1, 256, 0, stream>>>(
        xin, proj_W + (size_t)l * 768 * 768, proj_b + l * 768, h_in,
        2048, 768, 768, 768, 768, nullptr, nullptr, nullptr, 0, 0);

    dim3 g2(18, 16);
    gemm_nt<false, false, false, false><<<g2, 256, 0, stream>>>(
        h_in, Wih, bih, gi,
        2048, 2304, 768, 768, 2304, nullptr, nullptr, nullptr, 0, 0);

    gru_kernel<<<192, 256, 0, stream>>>(gi, h_seq, hbuf, Whh, bhh,
                                        flags, flags + 6144, l * 512);

    router_kernel<<<2048, 64, 0, stream>>>(h_seq, rW + (size_t)l * 8 * 768,
                                           rb + l * 8, counts + l * 8, lists, gates);

    dim3 ga(24, 32, 8);
    gemm_nt<true, true, true, false><<<ga, 256, 0, stream>>>(
        xin, eW1 + (size_t)l * 8 * 3072 * 768, eb1 + (size_t)l * 8 * 3072, H1,
        4096, 3072, 768, 768, 3072, lists, counts + l * 8, nullptr,
        (long)3072 * 768, 3072);

    dim3 gb(6, 32, 8);
    gemm_nt<true, false, false, true><<<gb, 256, 0, stream>>>(
        H1, eW2 + (size_t)l * 8 * 768 * 3072, eb2 + (size_t)l * 8 * 768, ybuf,
        4096, 768, 3072, 3072, 768, lists, counts + l * 8, gates,
        (long)768 * 3072, 768);

    combine_kernel<<<1536, 256, 0, stream>>>(ybuf, l ? out : x_buf);
  }
}

// Round 2
// 11849.173 us; speedup vs baseline: 2.8450x; 2.8450x over previous
//
#include <hip/hip_runtime.h>
#include <cmath>

#define AGENT __HIP_MEMORY_SCOPE_AGENT

// Problem constants
// B=4, S=512, I=H=768, 3H=2304, E=8, K=2, L=2, tokens=2048, assignments=4096

// ---------------- reset ----------------
__global__ void reset_kernel(int* __restrict__ flags, int* __restrict__ counts,
                             float* __restrict__ hbuf0) {
  int i = blockIdx.x * 256 + threadIdx.x;
  if (i < 6208) flags[i] = 0;          // barrier counter (flags[0]) + slack
  if (i < 16) counts[i] = 0;           // counts[2][8]
  if (i < 3072) hbuf0[i] = 0.f;        // h0 = zeros (layer 0)
}

// ---------------- GEMM: C = op(A @ B^T + bias) ----------------
// A [M x Kd] row-major (lda), B [N x Kd] row-major, C rows scattered if GATHER.
// Tile 128x128x16, 256 threads, 8x8 acc/thread (2x2 blocks of 4x4).
template<bool GATHER, bool SHIFT, bool RELU, bool GATE>
__global__ __launch_bounds__(256)
void gemm_nt(const float* __restrict__ A, const float* __restrict__ Bw,
             const float* __restrict__ bias, float* __restrict__ C,
             int M, int N, int Kd, int lda, int ldc,
             const int* __restrict__ list, const int* __restrict__ count,
             const float* __restrict__ gates, long wstride, int bstride)
{
  __shared__ float As[16][132];
  __shared__ float Bs[16][132];
  __shared__ int rowlist[128];

  int e = 0, cnt = M;
  if constexpr (GATHER) { e = blockIdx.z; cnt = count[e]; }
  int mbase = blockIdx.y * 128;
  if (mbase >= cnt) return;
  int nbase = blockIdx.x * 128;
  const float* Bp = Bw + (size_t)e * (size_t)wstride;
  const float* biasp = bias + (size_t)e * (size_t)bstride;

  int tid = threadIdx.x;
  if constexpr (GATHER) {
    if (tid < 128) {
      int r = mbase + tid;
      rowlist[tid] = list[e * 4096 + (r < cnt ? r : cnt - 1)];
    }
    __syncthreads();
  }

  int tx = tid & 15, ty = tid >> 4;

  const float* ap[2];
  const float* bp[2];
  int ldst[2];
#pragma unroll
  for (int i = 0; i < 2; ++i) {
    int v = tid + 256 * i;
    int row = v >> 2, kq = v & 3;
    const float* a0;
    if constexpr (GATHER) {
      int aidx = rowlist[row];
      int sr = SHIFT ? (aidx >> 1) : aidx;
      a0 = A + (size_t)sr * lda;
    } else {
      a0 = A + (size_t)(mbase + row) * lda;
    }
    ap[i] = a0 + kq * 4;
    bp[i] = Bp + (size_t)(nbase + row) * Kd + kq * 4;
    ldst[i] = kq * 4 * 132 + row;
  }

  float acc[8][8];
#pragma unroll
  for (int i = 0; i < 8; ++i)
#pragma unroll
    for (int j = 0; j < 8; ++j) acc[i][j] = 0.f;

  for (int kb = 0; kb < Kd; kb += 16) {
    float4 av[2], bv[2];
#pragma unroll
    for (int i = 0; i < 2; ++i) {
      av[i] = *(const float4*)(ap[i] + kb);
      bv[i] = *(const float4*)(bp[i] + kb);
    }
    if (kb) __syncthreads();
#pragma unroll
    for (int i = 0; i < 2; ++i) {
      float* ad = &As[0][0] + ldst[i];
      ad[0] = av[i].x; ad[132] = av[i].y; ad[264] = av[i].z; ad[396] = av[i].w;
      float* bd = &Bs[0][0] + ldst[i];
      bd[0] = bv[i].x; bd[132] = bv[i].y; bd[264] = bv[i].z; bd[396] = bv[i].w;
    }
    __syncthreads();
#pragma unroll
    for (int kk = 0; kk < 16; ++kk) {
      float a[8], b[8];
      *(float4*)&a[0] = *(const float4*)&As[kk][ty * 4];
      *(float4*)&a[4] = *(const float4*)&As[kk][ty * 4 + 64];
      *(float4*)&b[0] = *(const float4*)&Bs[kk][tx * 4];
      *(float4*)&b[4] = *(const float4*)&Bs[kk][tx * 4 + 64];
#pragma unroll
      for (int i = 0; i < 8; ++i)
#pragma unroll
        for (int j = 0; j < 8; ++j)
          acc[i][j] = fmaf(a[i], b[j], acc[i][j]);
    }
  }

#pragma unroll
  for (int i = 0; i < 8; ++i) {
    int lrow = ty * 4 + (i & 3) + ((i >> 2) << 6);
    int grow = mbase + lrow;
    bool ok = true;
    int orow = grow;
    float gs = 1.f;
    if constexpr (GATHER) {
      ok = (grow < cnt);
      int aidx = rowlist[lrow];
      orow = aidx;
      if constexpr (GATE) gs = gates[aidx];
    }
    if (ok) {
#pragma unroll
      for (int q = 0; q < 2; ++q) {
        int col = nbase + tx * 4 + (q << 6);
        float4 bb = *(const float4*)&biasp[col];
        float r0 = acc[i][q * 4 + 0] + bb.x;
        float r1 = acc[i][q * 4 + 1] + bb.y;
        float r2 = acc[i][q * 4 + 2] + bb.z;
        float r3 = acc[i][q * 4 + 3] + bb.w;
        if constexpr (RELU) {
          r0 = fmaxf(r0, 0.f); r1 = fmaxf(r1, 0.f);
          r2 = fmaxf(r2, 0.f); r3 = fmaxf(r3, 0.f);
        }
        if constexpr (GATE) { r0 *= gs; r1 *= gs; r2 *= gs; r3 *= gs; }
        float4 st = make_float4(r0, r1, r2, r3);
        *(float4*)&C[(size_t)orow * ldc + col] = st;
      }
    }
  }
}

// ---------------- GRU persistent kernel ----------------
// 192 WGs x 256 threads = 768 waves; wave w owns output column j.
// Whh rows {j, H+j, 2H+j} live in registers (lane holds k-slice of 12).
// Cross-WG h exchange via fine-grained coherent (relaxed agent atomic,
// sc0 sc1 -> LLC) loads/stores: NO acquire/release cache-maintenance ops.
// Barrier = single monotonic LLC counter: each WG adds 1 after its stores
// retired (vmcnt(0)); tid0 polls ctr >= 192*(step+1) with relaxed loads.
__global__ __launch_bounds__(256)
void gru_kernel(const float* __restrict__ gi, float* __restrict__ h_seq,
                float* __restrict__ hbuf, const float* __restrict__ Whh,
                const float* __restrict__ bhh,
                int* __restrict__ ctr, int stepBase)
{
  const int H = 768, S = 512;
  int wg = blockIdx.x;
  int tid = threadIdx.x;
  int wave = tid >> 6;
  int lane = tid & 63;
  int j = wg * 4 + wave;

  float W[3][12];
#pragma unroll
  for (int g = 0; g < 3; ++g) {
    const float* wp = Whh + (size_t)(g * H + j) * H + lane * 12;
    *(float4*)&W[g][0] = *(const float4*)(wp);
    *(float4*)&W[g][4] = *(const float4*)(wp + 4);
    *(float4*)&W[g][8] = *(const float4*)(wp + 8);
  }
  float bh_r = bhh[j], bh_z = bhh[H + j], bh_n = bhh[2 * H + j];

  float h_own = 0.f;
  if (lane < 4)
    h_own = __hip_atomic_load(&hbuf[(stepBase & 1) * 3072 + lane * H + j],
                              __ATOMIC_RELAXED, AGENT);

  for (int t = 0; t < S; ++t) {
    int gstep = stepBase + t;
    const float* hb = hbuf + (gstep & 1) * 3072;
    float* hw = hbuf + ((gstep + 1) & 1) * 3072;

    float gi_r = 0.f, gi_z = 0.f, gi_n = 0.f;
    if (lane < 4) {
      const float* gp = gi + ((size_t)lane * S + t) * 2304;
      gi_r = gp[j]; gi_z = gp[H + j]; gi_n = gp[2 * H + j];
    }

    // full h broadcast, straight from LLC (bypass stale L1/L2)
    float hseg[4][12];
#pragma unroll
    for (int b = 0; b < 4; ++b)
#pragma unroll
      for (int i = 0; i < 12; ++i)
        hseg[b][i] = __hip_atomic_load(&hb[b * H + lane * 12 + i],
                                       __ATOMIC_RELAXED, AGENT);

    float acc[3][4];
#pragma unroll
    for (int g = 0; g < 3; ++g)
#pragma unroll
      for (int b = 0; b < 4; ++b) {
        float s = 0.f;
#pragma unroll
        for (int i = 0; i < 12; ++i) s = fmaf(W[g][i], hseg[b][i], s);
        acc[g][b] = s;
      }
#pragma unroll
    for (int g = 0; g < 3; ++g)
#pragma unroll
      for (int b = 0; b < 4; ++b) {
        float v = acc[g][b];
#pragma unroll
        for (int m = 32; m >= 1; m >>= 1) v += __shfl_xor(v, m);
        acc[g][b] = v;
      }

    if (lane < 4) {
      int b = lane;
      float r = 1.f / (1.f + expf(-(gi_r + acc[0][b] + bh_r)));
      float z = 1.f / (1.f + expf(-(gi_z + acc[1][b] + bh_z)));
      float n = tanhf(gi_n + r * (acc[2][b] + bh_n));
      float hn = (1.f - z) * n + z * h_own;
      h_own = hn;
      __hip_atomic_store(&hw[b * H + j], hn, __ATOMIC_RELAXED, AGENT);
      h_seq[((size_t)b * S + t) * H + j] = hn;   // normal store, read post-kernel
    }

    // ---- lightweight grid barrier: no L2 writeback/invalidate ----
    asm volatile("s_waitcnt vmcnt(0)" ::: "memory");  // h stores are at LLC
    __syncthreads();                                  // whole WG retired
    if (tid == 0) {
      __hip_atomic_fetch_add(ctr, 1, __ATOMIC_RELAXED, AGENT);
      int target = 192 * (gstep + 1);
      while (__hip_atomic_load(ctr, __ATOMIC_RELAXED, AGENT) < target)
        __builtin_amdgcn_s_sleep(1);
    }
    __syncthreads();
  }
}

// ---------------- router + top-2 + gates + expert lists ----------------
__global__ __launch_bounds__(64)
void router_kernel(const float* __restrict__ h_seq, const float* __restrict__ rW,
                   const float* __restrict__ rb, int* __restrict__ counts,
                   int* __restrict__ lists, float* __restrict__ gates)
{
  int t = blockIdx.x;       // token 0..2047
  int lane = threadIdx.x;   // 0..63
  const float* hp = h_seq + (size_t)t * 768 + lane * 12;
  float h[12];
  *(float4*)&h[0] = *(const float4*)(hp);
  *(float4*)&h[4] = *(const float4*)(hp + 4);
  *(float4*)&h[8] = *(const float4*)(hp + 8);

  float lg[8];
#pragma unroll
  for (int e = 0; e < 8; ++e) {
    const float* wp = rW + e * 768 + lane * 12;
    float s = 0.f;
#pragma unroll
    for (int i = 0; i < 12; ++i) s = fmaf(h[i], wp[i], s);
#pragma unroll
    for (int m = 32; m >= 1; m >>= 1) s += __shfl_xor(s, m);
    lg[e] = s + rb[e];
  }
  if (lane == 0) {
    float v1 = lg[0]; int e1 = 0;
#pragma unroll
    for (int e = 1; e < 8; ++e) {
      if (lg[e] > v1) { v1 = lg[e]; e1 = e; }
    }
    float v2 = -INFINITY; int es = 0;
#pragma unroll
    for (int e = 0; e < 8; ++e) {
      if (e != e1 && lg[e] > v2) { v2 = lg[e]; es = e; }
    }
    float ed = expf(v2 - v1);
    float g1 = 1.f / (1.f + ed);
    float g2 = ed / (1.f + ed);
    int a0 = t * 2, a1 = t * 2 + 1;
    gates[a0] = g1;
    gates[a1] = g2;
    int p = atomicAdd(&counts[e1], 1);
    lists[e1 * 4096 + p] = a0;
    p = atomicAdd(&counts[es], 1);
    lists[es * 4096 + p] = a1;
  }
}

// ---------------- combine: x_next[t] = ybuf[2t] + ybuf[2t+1] ----------------
__global__ __launch_bounds__(256)
void combine_kernel(const float* __restrict__ ybuf, float* __restrict__ out)
{
  int i = blockIdx.x * 256 + threadIdx.x;     // one float4 each
  int fi = i * 4;                              // < 2048*768
  int t = fi / 768;
  int d = fi % 768;
  float4 y0 = *(const float4*)&ybuf[(size_t)(2 * t) * 768 + d];
  float4 y1 = *(const float4*)&ybuf[(size_t)(2 * t + 1) * 768 + d];
  float4 r = make_float4(y0.x + y1.x, y0.y + y1.y, y0.z + y1.z, y0.w + y1.w);
  *(float4*)&out[fi] = r;
}

// ---------------- host ----------------
extern "C" void kernel_launch(void* const* d_in, const int* in_sizes, int n_in,
                              void* d_out, int out_size, void* d_ws, size_t ws_size,
                              hipStream_t stream) {
  (void)in_sizes; (void)n_in; (void)out_size; (void)ws_size;
  const float* x      = (const float*)d_in[0];
  const float* proj_W = (const float*)d_in[1];
  const float* proj_b = (const float*)d_in[2];
  const float* Wih    = (const float*)d_in[3];
  const float* Whh    = (const float*)d_in[4];
  const float* bih    = (const float*)d_in[5];
  const float* bhh    = (const float*)d_in[6];
  const float* rW     = (const float*)d_in[7];
  const float* rb     = (const float*)d_in[8];
  const float* eW1    = (const float*)d_in[9];
  const float* eb1    = (const float*)d_in[10];
  const float* eW2    = (const float*)d_in[11];
  const float* eb2    = (const float*)d_in[12];
  float* out = (float*)d_out;

  // workspace layout (floats)
  float* f = (float*)d_ws;
  float* h_in  = f;                    // 2048*768
  float* gi    = h_in + 1572864;       // 2048*2304
  float* h_seq = gi + 4718592;         // 2048*768
  float* x_buf = h_seq + 1572864;      // 2048*768
  float* H1    = x_buf + 1572864;      // 4096*3072
  float* ybuf  = H1 + 12582912;        // 4096*768
  float* hbuf  = ybuf + 3145728;       // 2*3072
  float* gates = hbuf + 6144;          // 4096
  int* ints    = (int*)(gates + 4096);
  int* counts  = ints;                 // 16
  int* lists   = ints + 16;            // 8*4096
  int* flags   = ints + 16 + 32768;    // barrier counter at flags[0]

  reset_kernel<<<25, 256, 0, stream>>>(flags, counts, hbuf);

  for (int l = 0; l < 2; ++l) {
    const float* xin = l ? x_buf : x;

    dim3 g1(6, 16);
    gemm_nt<false, false, false, false><<<g1, 256, 0, stream>>>(
        xin, proj_W + (size_t)l * 768 * 768, proj_b + l * 768, h_in,
        2048, 768, 768, 768, 768, nullptr, nullptr, nullptr, 0, 0);

    dim3 g2(18, 16);
    gemm_nt<false, false, false, false><<<g2, 256, 0, stream>>>(
        h_in, Wih, bih, gi,
        2048, 2304, 768, 768, 2304, nullptr, nullptr, nullptr, 0, 0);

    gru_kernel<<<192, 256, 0, stream>>>(gi, h_seq, hbuf, Whh, bhh,
                                        flags, l * 512);

    router_kernel<<<2048, 64, 0, stream>>>(h_seq, rW + (size_t)l * 8 * 768,
                                           rb + l * 8, counts + l * 8, lists, gates);

    dim3 ga(24, 32, 8);
    gemm_nt<true, true, true, false><<<ga, 256, 0, stream>>>(
        xin, eW1 + (size_t)l * 8 * 3072 * 768, eb1 + (size_t)l * 8 * 3072, H1,
        4096, 3072, 768, 768, 3072, lists, counts + l * 8, nullptr,
        (long)3072 * 768, 3072);

    dim3 gb(6, 32, 8);
    gemm_nt<true, false, false, true><<<gb, 256, 0, stream>>>(
        H1, eW2 + (size_t)l * 8 * 768 * 3072, eb2 + (size_t)l * 8 * 768, ybuf,
        4096, 768, 3072, 3072, 768, lists, counts + l * 8, gates,
        (long)768 * 3072, 768);

    combine_kernel<<<1536, 256, 0, stream>>>(ybuf, l ? out : x_buf);
  }
}

// Round 7
// 9699.933 us; speedup vs baseline: 3.4754x; 1.2216x over previous
//
#include <hip/hip_runtime.h>
#include <cmath>

#define AGENT __HIP_MEMORY_SCOPE_AGENT

// Problem constants
// B=4, S=512, I=H=768, 3H=2304, E=8, K=2, L=2, tokens=2048, assignments=4096

// ---------------- reset ----------------
__global__ void reset_kernel(int* __restrict__ flags, int* __restrict__ counts,
                             float* __restrict__ hbuf0) {
  int i = blockIdx.x * 256 + threadIdx.x;
  if (i < 6208) flags[i] = 0;          // barrier counter (flags[0]) + slack
  if (i < 16) counts[i] = 0;           // counts[2][8]
  if (i < 3072) hbuf0[i] = 0.f;        // h0 = zeros (layer 0)
}

// ---------------- GEMM: C = op(A @ B^T + bias) ----------------
// A [M x Kd] row-major (lda), B [N x Kd] row-major, C rows scattered if GATHER.
// Tile 128x128x16, 256 threads, 8x8 acc/thread (2x2 blocks of 4x4).
template<bool GATHER, bool SHIFT, bool RELU, bool GATE>
__global__ __launch_bounds__(256)
void gemm_nt(const float* __restrict__ A, const float* __restrict__ Bw,
             const float* __restrict__ bias, float* __restrict__ C,
             int M, int N, int Kd, int lda, int ldc,
             const int* __restrict__ list, const int* __restrict__ count,
             const float* __restrict__ gates, long wstride, int bstride)
{
  __shared__ float As[16][132];
  __shared__ float Bs[16][132];
  __shared__ int rowlist[128];

  int e = 0, cnt = M;
  if constexpr (GATHER) { e = blockIdx.z; cnt = count[e]; }
  int mbase = blockIdx.y * 128;
  if (mbase >= cnt) return;
  int nbase = blockIdx.x * 128;
  const float* Bp = Bw + (size_t)e * (size_t)wstride;
  const float* biasp = bias + (size_t)e * (size_t)bstride;

  int tid = threadIdx.x;
  if constexpr (GATHER) {
    if (tid < 128) {
      int r = mbase + tid;
      rowlist[tid] = list[e * 4096 + (r < cnt ? r : cnt - 1)];
    }
    __syncthreads();
  }

  int tx = tid & 15, ty = tid >> 4;

  const float* ap[2];
  const float* bp[2];
  int ldst[2];
#pragma unroll
  for (int i = 0; i < 2; ++i) {
    int v = tid + 256 * i;
    int row = v >> 2, kq = v & 3;
    const float* a0;
    if constexpr (GATHER) {
      int aidx = rowlist[row];
      int sr = SHIFT ? (aidx >> 1) : aidx;
      a0 = A + (size_t)sr * lda;
    } else {
      a0 = A + (size_t)(mbase + row) * lda;
    }
    ap[i] = a0 + kq * 4;
    bp[i] = Bp + (size_t)(nbase + row) * Kd + kq * 4;
    ldst[i] = kq * 4 * 132 + row;
  }

  float acc[8][8];
#pragma unroll
  for (int i = 0; i < 8; ++i)
#pragma unroll
    for (int j = 0; j < 8; ++j) acc[i][j] = 0.f;

  for (int kb = 0; kb < Kd; kb += 16) {
    float4 av[2], bv[2];
#pragma unroll
    for (int i = 0; i < 2; ++i) {
      av[i] = *(const float4*)(ap[i] + kb);
      bv[i] = *(const float4*)(bp[i] + kb);
    }
    if (kb) __syncthreads();
#pragma unroll
    for (int i = 0; i < 2; ++i) {
      float* ad = &As[0][0] + ldst[i];
      ad[0] = av[i].x; ad[132] = av[i].y; ad[264] = av[i].z; ad[396] = av[i].w;
      float* bd = &Bs[0][0] + ldst[i];
      bd[0] = bv[i].x; bd[132] = bv[i].y; bd[264] = bv[i].z; bd[396] = bv[i].w;
    }
    __syncthreads();
#pragma unroll
    for (int kk = 0; kk < 16; ++kk) {
      float a[8], b[8];
      *(float4*)&a[0] = *(const float4*)&As[kk][ty * 4];
      *(float4*)&a[4] = *(const float4*)&As[kk][ty * 4 + 64];
      *(float4*)&b[0] = *(const float4*)&Bs[kk][tx * 4];
      *(float4*)&b[4] = *(const float4*)&Bs[kk][tx * 4 + 64];
#pragma unroll
      for (int i = 0; i < 8; ++i)
#pragma unroll
        for (int j = 0; j < 8; ++j)
          acc[i][j] = fmaf(a[i], b[j], acc[i][j]);
    }
  }

#pragma unroll
  for (int i = 0; i < 8; ++i) {
    int lrow = ty * 4 + (i & 3) + ((i >> 2) << 6);
    int grow = mbase + lrow;
    bool ok = true;
    int orow = grow;
    float gs = 1.f;
    if constexpr (GATHER) {
      ok = (grow < cnt);
      int aidx = rowlist[lrow];
      orow = aidx;
      if constexpr (GATE) gs = gates[aidx];
    }
    if (ok) {
#pragma unroll
      for (int q = 0; q < 2; ++q) {
        int col = nbase + tx * 4 + (q << 6);
        float4 bb = *(const float4*)&biasp[col];
        float r0 = acc[i][q * 4 + 0] + bb.x;
        float r1 = acc[i][q * 4 + 1] + bb.y;
        float r2 = acc[i][q * 4 + 2] + bb.z;
        float r3 = acc[i][q * 4 + 3] + bb.w;
        if constexpr (RELU) {
          r0 = fmaxf(r0, 0.f); r1 = fmaxf(r1, 0.f);
          r2 = fmaxf(r2, 0.f); r3 = fmaxf(r3, 0.f);
        }
        if constexpr (GATE) { r0 *= gs; r1 *= gs; r2 *= gs; r3 *= gs; }
        float4 st = make_float4(r0, r1, r2, r3);
        *(float4*)&C[(size_t)orow * ldc + col] = st;
      }
    }
  }
}

// ---------------- GRU persistent kernel ----------------
// 96 WGs x 512 threads = 768 waves; wave w owns output column j = wg*8+wave.
// Whh rows {j, H+j, 2H+j} live in registers (lane holds float4-strided slice).
// Per step: WG stages full h [4x768] into LDS via COALESCED coherent
// global_load_dwordx4 sc0 sc1 (768 requests/WG, vs 12K scalar before);
// waves read fragments from LDS; 64-lane butterfly reduce; lanes 0..3 do
// gate math and store h_new coherently; single LLC counter barrier.
__global__ __launch_bounds__(512)
void gru_kernel(const float* __restrict__ gi, float* __restrict__ h_seq,
                float* __restrict__ hbuf, const float* __restrict__ Whh,
                const float* __restrict__ bhh,
                int* __restrict__ ctr, int stepBase)
{
  const int H = 768, S = 512;
  __shared__ float hs[3072];
  int wg = blockIdx.x;           // 0..95
  int tid = threadIdx.x;         // 0..511
  int wave = tid >> 6;           // 0..7
  int lane = tid & 63;
  int j = wg * 8 + wave;

  // W[g][q*4+k] = Whh[g*H+j][q*256 + lane*4 + k]
  float W[3][12];
#pragma unroll
  for (int g = 0; g < 3; ++g) {
    const float* wp = Whh + (size_t)(g * H + j) * H + lane * 4;
    *(float4*)&W[g][0] = *(const float4*)(wp);
    *(float4*)&W[g][4] = *(const float4*)(wp + 256);
    *(float4*)&W[g][8] = *(const float4*)(wp + 512);
  }
  float bh_r = bhh[j], bh_z = bhh[H + j], bh_n = bhh[2 * H + j];

  float h_own = 0.f;
  if (lane < 4)
    h_own = __hip_atomic_load(&hbuf[(stepBase & 1) * 3072 + lane * H + j],
                              __ATOMIC_RELAXED, AGENT);

  for (int t = 0; t < S; ++t) {
    int gstep = stepBase + t;
    const float* hb = hbuf + (gstep & 1) * 3072;
    float* hw = hbuf + ((gstep + 1) & 1) * 3072;

    // gi loads (normal cached; run parallel to the coherent h staging)
    float gi_r = 0.f, gi_z = 0.f, gi_n = 0.f;
    if (lane < 4) {
      const float* gp = gi + ((size_t)lane * S + t) * 2304;
      gi_r = gp[j]; gi_z = gp[H + j]; gi_n = gp[2 * H + j];
    }

    // ---- stage h into LDS: 768 coherent float4 loads across the WG ----
    float4 a, b;
    asm volatile("global_load_dwordx4 %0, %1, off sc0 sc1"
                 : "=v"(a) : "v"(hb + tid * 4) : "memory");
    if (tid < 256)   // wave-uniform branch (waves 0..3)
      asm volatile("global_load_dwordx4 %0, %1, off sc0 sc1"
                   : "=v"(b) : "v"(hb + 2048 + tid * 4) : "memory");
    // volatile + "memory" clobber orders the following LDS writes (memory
    // ops) after the waitcnt; sched_barrier pins the scheduler too.
    asm volatile("s_waitcnt vmcnt(0)" ::: "memory");
    __builtin_amdgcn_sched_barrier(0);
    *(float4*)&hs[tid * 4] = a;
    if (tid < 256) *(float4*)&hs[2048 + tid * 4] = b;
    __syncthreads();

    // ---- fragments from LDS (conflict-free contiguous b128) ----
    float hseg[4][12];
#pragma unroll
    for (int b4 = 0; b4 < 4; ++b4) {
      *(float4*)&hseg[b4][0] = *(const float4*)&hs[b4 * 768 + lane * 4];
      *(float4*)&hseg[b4][4] = *(const float4*)&hs[b4 * 768 + 256 + lane * 4];
      *(float4*)&hseg[b4][8] = *(const float4*)&hs[b4 * 768 + 512 + lane * 4];
    }

    float acc[3][4];
#pragma unroll
    for (int g = 0; g < 3; ++g)
#pragma unroll
      for (int b4 = 0; b4 < 4; ++b4) {
        float s = 0.f;
#pragma unroll
        for (int i = 0; i < 12; ++i) s = fmaf(W[g][i], hseg[b4][i], s);
        acc[g][b4] = s;
      }
#pragma unroll
    for (int g = 0; g < 3; ++g)
#pragma unroll
      for (int b4 = 0; b4 < 4; ++b4) {
        float v = acc[g][b4];
#pragma unroll
        for (int m = 32; m >= 1; m >>= 1) v += __shfl_xor(v, m);
        acc[g][b4] = v;
      }

    if (lane < 4) {
      // static selects (no runtime register-array index -> no scratch)
      float ar = acc[0][0], az = acc[1][0], an = acc[2][0];
      if (lane == 1) { ar = acc[0][1]; az = acc[1][1]; an = acc[2][1]; }
      if (lane == 2) { ar = acc[0][2]; az = acc[1][2]; an = acc[2][2]; }
      if (lane == 3) { ar = acc[0][3]; az = acc[1][3]; an = acc[2][3]; }
      float r = 1.f / (1.f + expf(-(gi_r + ar + bh_r)));
      float z = 1.f / (1.f + expf(-(gi_z + az + bh_z)));
      float n = tanhf(gi_n + r * (an + bh_n));
      float hn = (1.f - z) * n + z * h_own;
      h_own = hn;
      __hip_atomic_store(&hw[lane * H + j], hn, __ATOMIC_RELAXED, AGENT);
      h_seq[((size_t)lane * S + t) * H + j] = hn;   // read post-kernel
    }

    // ---- lightweight grid barrier: no L2 writeback/invalidate ----
    asm volatile("s_waitcnt vmcnt(0)" ::: "memory");  // h stores at LLC
    __syncthreads();                                  // whole WG retired
    if (tid == 0) {
      __hip_atomic_fetch_add(ctr, 1, __ATOMIC_RELAXED, AGENT);
      int target = 96 * (gstep + 1);
      while (__hip_atomic_load(ctr, __ATOMIC_RELAXED, AGENT) < target)
        __builtin_amdgcn_s_sleep(1);
    }
    __syncthreads();
  }
}

// ---------------- router + top-2 + gates + expert lists ----------------
__global__ __launch_bounds__(64)
void router_kernel(const float* __restrict__ h_seq, const float* __restrict__ rW,
                   const float* __restrict__ rb, int* __restrict__ counts,
                   int* __restrict__ lists, float* __restrict__ gates)
{
  int t = blockIdx.x;       // token 0..2047
  int lane = threadIdx.x;   // 0..63
  const float* hp = h_seq + (size_t)t * 768 + lane * 12;
  float h[12];
  *(float4*)&h[0] = *(const float4*)(hp);
  *(float4*)&h[4] = *(const float4*)(hp + 4);
  *(float4*)&h[8] = *(const float4*)(hp + 8);

  float lg[8];
#pragma unroll
  for (int e = 0; e < 8; ++e) {
    const float* wp = rW + e * 768 + lane * 12;
    float s = 0.f;
#pragma unroll
    for (int i = 0; i < 12; ++i) s = fmaf(h[i], wp[i], s);
#pragma unroll
    for (int m = 32; m >= 1; m >>= 1) s += __shfl_xor(s, m);
    lg[e] = s + rb[e];
  }
  if (lane == 0) {
    float v1 = lg[0]; int e1 = 0;
#pragma unroll
    for (int e = 1; e < 8; ++e) {
      if (lg[e] > v1) { v1 = lg[e]; e1 = e; }
    }
    float v2 = -INFINITY; int es = 0;
#pragma unroll
    for (int e = 0; e < 8; ++e) {
      if (e != e1 && lg[e] > v2) { v2 = lg[e]; es = e; }
    }
    float ed = expf(v2 - v1);
    float g1 = 1.f / (1.f + ed);
    float g2 = ed / (1.f + ed);
    int a0 = t * 2, a1 = t * 2 + 1;
    gates[a0] = g1;
    gates[a1] = g2;
    int p = atomicAdd(&counts[e1], 1);
    lists[e1 * 4096 + p] = a0;
    p = atomicAdd(&counts[es], 1);
    lists[es * 4096 + p] = a1;
  }
}

// ---------------- combine: x_next[t] = ybuf[2t] + ybuf[2t+1] ----------------
__global__ __launch_bounds__(256)
void combine_kernel(const float* __restrict__ ybuf, float* __restrict__ out)
{
  int i = blockIdx.x * 256 + threadIdx.x;     // one float4 each
  int fi = i * 4;                              // < 2048*768
  int t = fi / 768;
  int d = fi % 768;
  float4 y0 = *(const float4*)&ybuf[(size_t)(2 * t) * 768 + d];
  float4 y1 = *(const float4*)&ybuf[(size_t)(2 * t + 1) * 768 + d];
  float4 r = make_float4(y0.x + y1.x, y0.y + y1.y, y0.z + y1.z, y0.w + y1.w);
  *(float4*)&out[fi] = r;
}

// ---------------- host ----------------
extern "C" void kernel_launch(void* const* d_in, const int* in_sizes, int n_in,
                              void* d_out, int out_size, void* d_ws, size_t ws_size,
                              hipStream_t stream) {
  (void)in_sizes; (void)n_in; (void)out_size; (void)ws_size;
  const float* x      = (const float*)d_in[0];
  const float* proj_W = (const float*)d_in[1];
  const float* proj_b = (const float*)d_in[2];
  const float* Wih    = (const float*)d_in[3];
  const float* Whh    = (const float*)d_in[4];
  const float* bih    = (const float*)d_in[5];
  const float* bhh    = (const float*)d_in[6];
  const float* rW     = (const float*)d_in[7];
  const float* rb     = (const float*)d_in[8];
  const float* eW1    = (const float*)d_in[9];
  const float* eb1    = (const float*)d_in[10];
  const float* eW2    = (const float*)d_in[11];
  const float* eb2    = (const float*)d_in[12];
  float* out = (float*)d_out;

  // workspace layout (floats)
  float* f = (float*)d_ws;
  float* h_in  = f;                    // 2048*768
  float* gi    = h_in + 1572864;       // 2048*2304
  float* h_seq = gi + 4718592;         // 2048*768
  float* x_buf = h_seq + 1572864;      // 2048*768
  float* H1    = x_buf + 1572864;      // 4096*3072
  float* ybuf  = H1 + 12582912;        // 4096*768
  float* hbuf  = ybuf + 3145728;       // 2*3072
  float* gates = hbuf + 6144;          // 4096
  int* ints    = (int*)(gates + 4096);
  int* counts  = ints;                 // 16
  int* lists   = ints + 16;            // 8*4096
  int* flags   = ints + 16 + 32768;    // barrier counter at flags[0]

  reset_kernel<<<25, 256, 0, stream>>>(flags, counts, hbuf);

  for (int l = 0; l < 2; ++l) {
    const float* xin = l ? x_buf : x;

    dim3 g1(6, 16);
    gemm_nt<false, false, false, false><<<g1, 256, 0, stream>>>(
        xin, proj_W + (size_t)l * 768 * 768, proj_b + l * 768, h_in,
        2048, 768, 768, 768, 768, nullptr, nullptr, nullptr, 0, 0);

    dim3 g2(18, 16);
    gemm_nt<false, false, false, false><<<g2, 256, 0, stream>>>(
        h_in, Wih, bih, gi,
        2048, 2304, 768, 768, 2304, nullptr, nullptr, nullptr, 0, 0);

    gru_kernel<<<96, 512, 0, stream>>>(gi, h_seq, hbuf, Whh, bhh,
                                       flags, l * 512);

    router_kernel<<<2048, 64, 0, stream>>>(h_seq, rW + (size_t)l * 8 * 768,
                                           rb + l * 8, counts + l * 8, lists, gates);

    dim3 ga(24, 32, 8);
    gemm_nt<true, true, true, false><<<ga, 256, 0, stream>>>(
        xin, eW1 + (size_t)l * 8 * 3072 * 768, eb1 + (size_t)l * 8 * 3072, H1,
        4096, 3072, 768, 768, 3072, lists, counts + l * 8, nullptr,
        (long)3072 * 768, 3072);

    dim3 gb(6, 32, 8);
    gemm_nt<true, false, false, true><<<gb, 256, 0, stream>>>(
        H1, eW2 + (size_t)l * 8 * 768 * 3072, eb2 + (size_t)l * 8 * 768, ybuf,
        4096, 768, 3072, 3072, 768, lists, counts + l * 8, gates,
        (long)768 * 3072, 768);

    combine_kernel<<<1536, 256, 0, stream>>>(ybuf, l ? out : x_buf);
  }
}

// Round 8
// 7629.551 us; speedup vs baseline: 4.4185x; 1.2714x over previous
//
#include <hip/hip_runtime.h>
#include <cmath>

#define AGENT __HIP_MEMORY_SCOPE_AGENT

// Problem constants
// B=4, S=512, I=H=768, 3H=2304, E=8, K=2, L=2, tokens=2048, assignments=4096

// ---------------- reset ----------------
__global__ void reset_kernel(int* __restrict__ flags, int* __restrict__ counts,
                             float* __restrict__ hbuf0) {
  int i = blockIdx.x * 256 + threadIdx.x;
  if (i < 6208) flags[i] = 0;          // tags[96*32] + slack
  if (i < 16) counts[i] = 0;           // counts[2][8]
  if (i < 3072) hbuf0[i] = 0.f;        // h0 = zeros (layer 0)
}

// ---------------- GEMM: C = op(A @ B^T + bias) ----------------
// A [M x Kd] row-major (lda), B [N x Kd] row-major, C rows scattered if GATHER.
// Tile 128x128x16, 256 threads, 8x8 acc/thread (2x2 blocks of 4x4).
// GI2: remap C store to gi2[t][wg][b][gate][8] layout for the GRU.
template<bool GATHER, bool SHIFT, bool RELU, bool GATE, bool GI2 = false>
__global__ __launch_bounds__(256)
void gemm_nt(const float* __restrict__ A, const float* __restrict__ Bw,
             const float* __restrict__ bias, float* __restrict__ C,
             int M, int N, int Kd, int lda, int ldc,
             const int* __restrict__ list, const int* __restrict__ count,
             const float* __restrict__ gates, long wstride, int bstride)
{
  __shared__ float As[16][132];
  __shared__ float Bs[16][132];
  __shared__ int rowlist[128];

  int e = 0, cnt = M;
  if constexpr (GATHER) { e = blockIdx.z; cnt = count[e]; }
  int mbase = blockIdx.y * 128;
  if (mbase >= cnt) return;
  int nbase = blockIdx.x * 128;
  const float* Bp = Bw + (size_t)e * (size_t)wstride;
  const float* biasp = bias + (size_t)e * (size_t)bstride;

  int tid = threadIdx.x;
  if constexpr (GATHER) {
    if (tid < 128) {
      int r = mbase + tid;
      rowlist[tid] = list[e * 4096 + (r < cnt ? r : cnt - 1)];
    }
    __syncthreads();
  }

  int tx = tid & 15, ty = tid >> 4;

  const float* ap[2];
  const float* bp[2];
  int ldst[2];
#pragma unroll
  for (int i = 0; i < 2; ++i) {
    int v = tid + 256 * i;
    int row = v >> 2, kq = v & 3;
    const float* a0;
    if constexpr (GATHER) {
      int aidx = rowlist[row];
      int sr = SHIFT ? (aidx >> 1) : aidx;
      a0 = A + (size_t)sr * lda;
    } else {
      a0 = A + (size_t)(mbase + row) * lda;
    }
    ap[i] = a0 + kq * 4;
    bp[i] = Bp + (size_t)(nbase + row) * Kd + kq * 4;
    ldst[i] = kq * 4 * 132 + row;
  }

  float acc[8][8];
#pragma unroll
  for (int i = 0; i < 8; ++i)
#pragma unroll
    for (int j = 0; j < 8; ++j) acc[i][j] = 0.f;

  for (int kb = 0; kb < Kd; kb += 16) {
    float4 av[2], bv[2];
#pragma unroll
    for (int i = 0; i < 2; ++i) {
      av[i] = *(const float4*)(ap[i] + kb);
      bv[i] = *(const float4*)(bp[i] + kb);
    }
    if (kb) __syncthreads();
#pragma unroll
    for (int i = 0; i < 2; ++i) {
      float* ad = &As[0][0] + ldst[i];
      ad[0] = av[i].x; ad[132] = av[i].y; ad[264] = av[i].z; ad[396] = av[i].w;
      float* bd = &Bs[0][0] + ldst[i];
      bd[0] = bv[i].x; bd[132] = bv[i].y; bd[264] = bv[i].z; bd[396] = bv[i].w;
    }
    __syncthreads();
#pragma unroll
    for (int kk = 0; kk < 16; ++kk) {
      float a[8], b[8];
      *(float4*)&a[0] = *(const float4*)&As[kk][ty * 4];
      *(float4*)&a[4] = *(const float4*)&As[kk][ty * 4 + 64];
      *(float4*)&b[0] = *(const float4*)&Bs[kk][tx * 4];
      *(float4*)&b[4] = *(const float4*)&Bs[kk][tx * 4 + 64];
#pragma unroll
      for (int i = 0; i < 8; ++i)
#pragma unroll
        for (int j = 0; j < 8; ++j)
          acc[i][j] = fmaf(a[i], b[j], acc[i][j]);
    }
  }

#pragma unroll
  for (int i = 0; i < 8; ++i) {
    int lrow = ty * 4 + (i & 3) + ((i >> 2) << 6);
    int grow = mbase + lrow;
    bool ok = true;
    int orow = grow;
    float gs = 1.f;
    if constexpr (GATHER) {
      ok = (grow < cnt);
      int aidx = rowlist[lrow];
      orow = aidx;
      if constexpr (GATE) gs = gates[aidx];
    }
    if (ok) {
#pragma unroll
      for (int q = 0; q < 2; ++q) {
        int col = nbase + tx * 4 + (q << 6);
        float4 bb = *(const float4*)&biasp[col];
        float r0 = acc[i][q * 4 + 0] + bb.x;
        float r1 = acc[i][q * 4 + 1] + bb.y;
        float r2 = acc[i][q * 4 + 2] + bb.z;
        float r3 = acc[i][q * 4 + 3] + bb.w;
        if constexpr (RELU) {
          r0 = fmaxf(r0, 0.f); r1 = fmaxf(r1, 0.f);
          r2 = fmaxf(r2, 0.f); r3 = fmaxf(r3, 0.f);
        }
        if constexpr (GATE) { r0 *= gs; r1 *= gs; r2 *= gs; r3 *= gs; }
        float4 st = make_float4(r0, r1, r2, r3);
        if constexpr (GI2) {
          // gi2[t][wg][b][gate][8]; col%8 in {0,4} so float4 stays in-octet
          int t = grow & 511, bb2 = grow >> 9;
          int gate = col / 768, jj = col - gate * 768;
          int wg2 = jj >> 3, o = jj & 7;
          float* dst = C + ((((size_t)t * 96 + wg2) * 4 + bb2) * 3 + gate) * 8 + o;
          *(float4*)dst = st;
        } else {
          *(float4*)&C[(size_t)orow * ldc + col] = st;
        }
      }
    }
  }
}

// ---------------- GRU persistent kernel ----------------
// 96 WGs x 512 threads; wave w owns output column j = wg*8+wave.
// Tag-gated producer/consumer: no atomics, no central barrier.
// Producer: store 32 h floats (coherent) -> vmcnt(0) -> syncthreads ->
//           tags[wg] = step+1 (own cache line).
// Consumer: wave0 polls all 96 tags >= step -> syncthreads -> WG bulk-loads
//           h [4x768] coherent into LDS -> compute.
// gi read from dense gi2[t][wg][b][gate][8] (12 lanes, shfl distribute).
// h_seq written coalesced from staged registers (one step delayed).
__global__ __launch_bounds__(512)
void gru_kernel(const float* __restrict__ gi2, float* __restrict__ h_seq,
                float* __restrict__ hbuf, const float* __restrict__ Whh,
                const float* __restrict__ bhh,
                int* __restrict__ tags, int stepBase)
{
  const int H = 768, S = 512;
  __shared__ float hs[3072];
  int wg = blockIdx.x;           // 0..95
  int tid = threadIdx.x;         // 0..511
  int wave = tid >> 6;           // 0..7
  int lane = tid & 63;
  int j = wg * 8 + wave;

  // W[g][q*4+k] = Whh[g*H+j][q*256 + lane*4 + k]
  float W[3][12];
#pragma unroll
  for (int g = 0; g < 3; ++g) {
    const float* wp = Whh + (size_t)(g * H + j) * H + lane * 4;
    *(float4*)&W[g][0] = *(const float4*)(wp);
    *(float4*)&W[g][4] = *(const float4*)(wp + 256);
    *(float4*)&W[g][8] = *(const float4*)(wp + 512);
  }
  float bh_r = bhh[j], bh_z = bhh[H + j], bh_n = bhh[2 * H + j];

  float h_own = 0.f;
  if (lane < 4)
    h_own = __hip_atomic_load(&hbuf[(stepBase & 1) * 3072 + lane * H + j],
                              __ATOMIC_RELAXED, AGENT);

  for (int tl = 0; tl < S; ++tl) {
    int g = stepBase + tl;
    const float* hb = hbuf + (g & 1) * 3072;
    float* hw = hbuf + ((g + 1) & 1) * 3072;

    // gi2 prefetch: lane i<12 loads element [b=i&3][gate=i>>2] for this wave's j
    float gv = 0.f;
    if (lane < 12)
      gv = gi2[(((size_t)tl * 96 + wg) * 12 + ((lane & 3) * 3 + (lane >> 2))) * 8 + wave];

    // ---- tag poll: wave0 waits until all 96 producers reached step g ----
    if (wave == 0) {
      for (;;) {
        int v1 = __hip_atomic_load(&tags[lane * 32], __ATOMIC_RELAXED, AGENT);
        int v2 = (lane < 32)
            ? __hip_atomic_load(&tags[(64 + lane) * 32], __ATOMIC_RELAXED, AGENT)
            : 0x7fffffff;
        if (__all(v1 >= g && v2 >= g)) break;
        __builtin_amdgcn_s_sleep(1);
      }
    }
    __syncthreads();

    // ---- stage h into LDS: coalesced coherent float4 loads ----
    float4 a, b4v;
    asm volatile("global_load_dwordx4 %0, %1, off sc0 sc1"
                 : "=v"(a) : "v"(hb + tid * 4) : "memory");
    if (tid < 256)   // wave-uniform (waves 0..3)
      asm volatile("global_load_dwordx4 %0, %1, off sc0 sc1"
                   : "=v"(b4v) : "v"(hb + 2048 + tid * 4) : "memory");
    asm volatile("s_waitcnt vmcnt(0)" ::: "memory");
    __builtin_amdgcn_sched_barrier(0);
    *(float4*)&hs[tid * 4] = a;
    if (tid < 256) *(float4*)&hs[2048 + tid * 4] = b4v;
    __syncthreads();

    // ---- coalesced h_seq write of the state we just staged (= h_seq[tl-1]) ----
    if (tl >= 1) {
      int i0 = tid * 4, bb = i0 / 768, d = i0 - bb * 768;
      *(float4*)&h_seq[((size_t)bb * S + (tl - 1)) * H + d] = a;
      if (tid < 256) {
        int i1 = 2048 + tid * 4, bb1 = i1 / 768, d1 = i1 - bb1 * 768;
        *(float4*)&h_seq[((size_t)bb1 * S + (tl - 1)) * H + d1] = b4v;
      }
    }

    // ---- fragments from LDS ----
    float hseg[4][12];
#pragma unroll
    for (int b4 = 0; b4 < 4; ++b4) {
      *(float4*)&hseg[b4][0] = *(const float4*)&hs[b4 * 768 + lane * 4];
      *(float4*)&hseg[b4][4] = *(const float4*)&hs[b4 * 768 + 256 + lane * 4];
      *(float4*)&hseg[b4][8] = *(const float4*)&hs[b4 * 768 + 512 + lane * 4];
    }

    float acc[3][4];
#pragma unroll
    for (int gg = 0; gg < 3; ++gg)
#pragma unroll
      for (int b4 = 0; b4 < 4; ++b4) {
        float s = 0.f;
#pragma unroll
        for (int i = 0; i < 12; ++i) s = fmaf(W[gg][i], hseg[b4][i], s);
        acc[gg][b4] = s;
      }
#pragma unroll
    for (int gg = 0; gg < 3; ++gg)
#pragma unroll
      for (int b4 = 0; b4 < 4; ++b4) {
        float v = acc[gg][b4];
#pragma unroll
        for (int m = 32; m >= 1; m >>= 1) v += __shfl_xor(v, m);
        acc[gg][b4] = v;
      }

    // gi distribute (all lanes participate in shfl)
    float gi_r = __shfl(gv, (lane & 3));
    float gi_z = __shfl(gv, 4 + (lane & 3));
    float gi_n = __shfl(gv, 8 + (lane & 3));

    if (lane < 4) {
      float ar = acc[0][0], az = acc[1][0], an = acc[2][0];
      if (lane == 1) { ar = acc[0][1]; az = acc[1][1]; an = acc[2][1]; }
      if (lane == 2) { ar = acc[0][2]; az = acc[1][2]; an = acc[2][2]; }
      if (lane == 3) { ar = acc[0][3]; az = acc[1][3]; an = acc[2][3]; }
      float r = 1.f / (1.f + expf(-(gi_r + ar + bh_r)));
      float z = 1.f / (1.f + expf(-(gi_z + az + bh_z)));
      float n = tanhf(gi_n + r * (an + bh_n));
      float hn = (1.f - z) * n + z * h_own;
      h_own = hn;
      __hip_atomic_store(&hw[lane * H + j], hn, __ATOMIC_RELAXED, AGENT);
    }

    // ---- publish: own stores acked -> all waves joined -> tag ----
    asm volatile("s_waitcnt vmcnt(0)" ::: "memory");
    __syncthreads();
    if (tid == 0)
      __hip_atomic_store(&tags[wg * 32], g + 1, __ATOMIC_RELAXED, AGENT);
  }

  // epilogue: each WG writes its own slice of h_seq[S-1] from registers
  if (lane < 4)
    h_seq[((size_t)lane * S + (S - 1)) * H + j] = h_own;
}

// ---------------- router + top-2 + gates + expert lists ----------------
__global__ __launch_bounds__(64)
void router_kernel(const float* __restrict__ h_seq, const float* __restrict__ rW,
                   const float* __restrict__ rb, int* __restrict__ counts,
                   int* __restrict__ lists, float* __restrict__ gates)
{
  int t = blockIdx.x;       // token 0..2047
  int lane = threadIdx.x;   // 0..63
  const float* hp = h_seq + (size_t)t * 768 + lane * 12;
  float h[12];
  *(float4*)&h[0] = *(const float4*)(hp);
  *(float4*)&h[4] = *(const float4*)(hp + 4);
  *(float4*)&h[8] = *(const float4*)(hp + 8);

  float lg[8];
#pragma unroll
  for (int e = 0; e < 8; ++e) {
    const float* wp = rW + e * 768 + lane * 12;
    float s = 0.f;
#pragma unroll
    for (int i = 0; i < 12; ++i) s = fmaf(h[i], wp[i], s);
#pragma unroll
    for (int m = 32; m >= 1; m >>= 1) s += __shfl_xor(s, m);
    lg[e] = s + rb[e];
  }
  if (lane == 0) {
    float v1 = lg[0]; int e1 = 0;
#pragma unroll
    for (int e = 1; e < 8; ++e) {
      if (lg[e] > v1) { v1 = lg[e]; e1 = e; }
    }
    float v2 = -INFINITY; int es = 0;
#pragma unroll
    for (int e = 0; e < 8; ++e) {
      if (e != e1 && lg[e] > v2) { v2 = lg[e]; es = e; }
    }
    float ed = expf(v2 - v1);
    float g1 = 1.f / (1.f + ed);
    float g2 = ed / (1.f + ed);
    int a0 = t * 2, a1 = t * 2 + 1;
    gates[a0] = g1;
    gates[a1] = g2;
    int p = atomicAdd(&counts[e1], 1);
    lists[e1 * 4096 + p] = a0;
    p = atomicAdd(&counts[es], 1);
    lists[es * 4096 + p] = a1;
  }
}

// ---------------- combine: x_next[t] = ybuf[2t] + ybuf[2t+1] ----------------
__global__ __launch_bounds__(256)
void combine_kernel(const float* __restrict__ ybuf, float* __restrict__ out)
{
  int i = blockIdx.x * 256 + threadIdx.x;     // one float4 each
  int fi = i * 4;                              // < 2048*768
  int t = fi / 768;
  int d = fi % 768;
  float4 y0 = *(const float4*)&ybuf[(size_t)(2 * t) * 768 + d];
  float4 y1 = *(const float4*)&ybuf[(size_t)(2 * t + 1) * 768 + d];
  float4 r = make_float4(y0.x + y1.x, y0.y + y1.y, y0.z + y1.z, y0.w + y1.w);
  *(float4*)&out[fi] = r;
}

// ---------------- host ----------------
extern "C" void kernel_launch(void* const* d_in, const int* in_sizes, int n_in,
                              void* d_out, int out_size, void* d_ws, size_t ws_size,
                              hipStream_t stream) {
  (void)in_sizes; (void)n_in; (void)out_size; (void)ws_size;
  const float* x      = (const float*)d_in[0];
  const float* proj_W = (const float*)d_in[1];
  const float* proj_b = (const float*)d_in[2];
  const float* Wih    = (const float*)d_in[3];
  const float* Whh    = (const float*)d_in[4];
  const float* bih    = (const float*)d_in[5];
  const float* bhh    = (const float*)d_in[6];
  const float* rW     = (const float*)d_in[7];
  const float* rb     = (const float*)d_in[8];
  const float* eW1    = (const float*)d_in[9];
  const float* eb1    = (const float*)d_in[10];
  const float* eW2    = (const float*)d_in[11];
  const float* eb2    = (const float*)d_in[12];
  float* out = (float*)d_out;

  // workspace layout (floats)
  float* f = (float*)d_ws;
  float* h_in  = f;                    // 2048*768
  float* gi2   = h_in + 1572864;       // 512*96*4*3*8 = 4718592
  float* h_seq = gi2 + 4718592;        // 2048*768
  float* x_buf = h_seq + 1572864;      // 2048*768
  float* H1    = x_buf + 1572864;      // 4096*3072
  float* ybuf  = H1 + 12582912;        // 4096*768
  float* hbuf  = ybuf + 3145728;       // 2*3072
  float* gates = hbuf + 6144;          // 4096
  int* ints    = (int*)(gates + 4096);
  int* counts  = ints;                 // 16
  int* lists   = ints + 16;            // 8*4096
  int* tags    = ints + 16 + 32768;    // 96*32 tags

  reset_kernel<<<25, 256, 0, stream>>>(tags, counts, hbuf);

  for (int l = 0; l < 2; ++l) {
    const float* xin = l ? x_buf : x;

    dim3 g1(6, 16);
    gemm_nt<false, false, false, false><<<g1, 256, 0, stream>>>(
        xin, proj_W + (size_t)l * 768 * 768, proj_b + l * 768, h_in,
        2048, 768, 768, 768, 768, nullptr, nullptr, nullptr, 0, 0);

    dim3 g2(18, 16);
    gemm_nt<false, false, false, false, true><<<g2, 256, 0, stream>>>(
        h_in, Wih, bih, gi2,
        2048, 2304, 768, 768, 0, nullptr, nullptr, nullptr, 0, 0);

    gru_kernel<<<96, 512, 0, stream>>>(gi2, h_seq, hbuf, Whh, bhh,
                                       tags, l * 512);

    router_kernel<<<2048, 64, 0, stream>>>(h_seq, rW + (size_t)l * 8 * 768,
                                           rb + l * 8, counts + l * 8, lists, gates);

    dim3 ga(24, 32, 8);
    gemm_nt<true, true, true, false><<<ga, 256, 0, stream>>>(
        xin, eW1 + (size_t)l * 8 * 3072 * 768, eb1 + (size_t)l * 8 * 3072, H1,
        4096, 3072, 768, 768, 3072, lists, counts + l * 8, nullptr,
        (long)3072 * 768, 3072);

    dim3 gb(6, 32, 8);
    gemm_nt<true, false, false, true><<<gb, 256, 0, stream>>>(
        H1, eW2 + (size_t)l * 8 * 768 * 3072, eb2 + (size_t)l * 8 * 768, ybuf,
        4096, 768, 3072, 3072, 768, lists, counts + l * 8, gates,
        (long)768 * 3072, 768);

    combine_kernel<<<1536, 256, 0, stream>>>(ybuf, l ? out : x_buf);
  }
}